// Round 16
// baseline (246.312 us; speedup 1.0000x reference)
//
#include <hip/hip_runtime.h>
#include <hip/hip_bf16.h>

typedef __attribute__((ext_vector_type(4))) int i32x4;
typedef unsigned char u8;

// ---------------- gamma = mean(|W|) + 1e-6, deterministic two-stage ----------------

__global__ void kabs_partial(const float* __restrict__ W, double* __restrict__ part, int n) {
    __shared__ double sd[256];
    const int tid = threadIdx.x;
    double s = 0.0;
    for (int i = blockIdx.x * blockDim.x + tid; i < n; i += gridDim.x * blockDim.x)
        s += (double)fabsf(W[i]);
    sd[tid] = s;
    __syncthreads();
    for (int off = 128; off > 0; off >>= 1) {
        if (tid < off) sd[tid] += sd[tid + off];
        __syncthreads();
    }
    if (tid == 0) part[blockIdx.x] = sd[0];
}

__global__ void kgamma(const double* __restrict__ part, float* __restrict__ gout, int nelem) {
    __shared__ double sd[256];
    const int tid = threadIdx.x;
    double s = part[tid] + part[tid + 256] + part[tid + 512] + part[tid + 768];
    sd[tid] = s;
    __syncthreads();
    for (int off = 128; off > 0; off >>= 1) {
        if (tid < off) sd[tid] += sd[tid + off];
        __syncthreads();
    }
    if (tid == 0) gout[0] = (float)(sd[0] / (double)nelem) + 1e-6f;
}

// ---------------- quantizers: write i8 {-1,0,+1} ----------------

__device__ __forceinline__ unsigned int qw_b(float w, float g) {
    float t = fabsf(w) / g;
    unsigned int u = __float_as_uint(w);
    return (rintf(t) >= 1.0f) ? ((u >> 31) ? 0xFFu : 0x01u) : 0u;
}

__global__ void kquant_w(const float4* __restrict__ W4, unsigned int* __restrict__ Wq,
                         const float* __restrict__ gptr, int n4) {
    int i = blockIdx.x * blockDim.x + threadIdx.x;
    if (i >= n4) return;
    const float g = *gptr;
    float4 w = W4[i];
    Wq[i] = qw_b(w.x, g) | (qw_b(w.y, g) << 8) | (qw_b(w.z, g) << 16) | (qw_b(w.w, g) << 24);
}

__device__ __forceinline__ unsigned int sgn_b(float a) {
    unsigned int u = __float_as_uint(a);
    return (u & 0x7FFFFFFFu) ? ((u >> 31) ? 0xFFu : 0x01u) : 0u;
}
__device__ __forceinline__ unsigned int sgn4(float4 v) {
    return sgn_b(v.x) | (sgn_b(v.y) << 8) | (sgn_b(v.z) << 16) | (sgn_b(v.w) << 24);
}

__global__ void kquant_x(const float4* __restrict__ X4, uint4* __restrict__ Xq, size_t n16) {
    size_t i = (size_t)blockIdx.x * blockDim.x + threadIdx.x;
    if (i >= n16) return;
    uint4 o;
    o.x = sgn4(X4[4 * i]);
    o.y = sgn4(X4[4 * i + 1]);
    o.z = sgn4(X4[4 * i + 2]);
    o.w = sgn4(X4[4 * i + 3]);
    Xq[i] = o;
}

// ---------------- 256x256 i8 MFMA GEMM: LDS-FREE, BARRIER-FREE ----------------
// C[M][N] = A[M][K] * B[N][K]^T, A/B i8 {-1,0,+1}, acc i32 (exact), out f32.
// R12-R15 lesson: with a 256^2 tile, acc=128 regs -> any dbuf'd operand set busts the
// 256-unified/wave budget, LDS tiles force 1 block/CU, and block-wide barriers make
// the MFMA/LDS/VALU windows SUM (5744cyc/tile measured vs 1400 max-pipe).
// Fix: no LDS, no barriers. A-frag loads are wave-coalesced from global (16 rows x
// 64B segments); B is 4MB, L2-resident. All 16 waves/CU drift freely; the compiler's
// counted vmcnt scheduling overlaps loads with the matrix pipe.
// Register contract (2 waves/SIMD): acc 128 (AGPR) + av 64 + bv 32, SINGLE-buffered
// with split-phase reload: after the ks=0 MFMA half (1306 cyc), av/bv[.][0] are dead
// and are reloaded for tile t+1 (WAR-safe); same for ks=1. Every load gets >=1306 cyc
// slack vs ~200-400 cyc L2 latency. sched_barrier(0) pins the load clusters between
// MFMA halves. Tail prefetch clamps to tile NT-1 (dead loads, drained at exit).

#define SB __builtin_amdgcn_sched_barrier(0)

#define GLOAD_A_KS(KS, KB)                                                                  \
    {                                                                                       \
        _Pragma("unroll")                                                                   \
        for (int mi = 0; mi < 8; ++mi)                                                      \
            av[mi][KS] = *(const i32x4*)(apb + (size_t)(((mi >> 2) * 128 + (mi & 3) * 16)) * K \
                                         + (KB) + (KS) * 64);                               \
    }
#define GLOAD_B_KS(KS, KB)                                                                  \
    {                                                                                       \
        _Pragma("unroll")                                                                   \
        for (int n = 0; n < 4; ++n)                                                         \
            bv[n][KS] = *(const i32x4*)(bpb + (size_t)(n * 16) * K + (KB) + (KS) * 64);     \
    }

// 32 MFMAs of one ks half: m0..7 x n0..3
#define MFMA_HALF(KS)                                                                       \
    do {                                                                                    \
        __builtin_amdgcn_s_setprio(1);                                                      \
        _Pragma("unroll")                                                                   \
        for (int mi = 0; mi < 8; ++mi)                                                      \
            _Pragma("unroll")                                                               \
            for (int n = 0; n < 4; ++n)                                                     \
                acc[mi][n] = __builtin_amdgcn_mfma_i32_16x16x64_i8(                         \
                    av[mi][KS], bv[n][KS], acc[mi][n], 0, 0, 0);                            \
        __builtin_amdgcn_s_setprio(0);                                                      \
    } while (0)

__global__ __launch_bounds__(512, 2) void kgemm(const u8* __restrict__ A,
                                                const u8* __restrict__ Bq,
                                                float* __restrict__ C,
                                                int M, int N, int K) {
    const int tid = threadIdx.x;
    const int lane = tid & 63;
    const int wid = tid >> 6;      // 0..7
    const int wm = wid >> 2;       // 0..1  (M sub-block within each half)
    const int wn = wid & 3;        // 0..3  (N sub-block)

    // T1: XCD-aware block swizzle (grid % 8 == 0 here)
    int bid = blockIdx.x;
    const int nwg = gridDim.x;
    if ((nwg & 7) == 0) bid = (bid & 7) * (nwg >> 3) + (bid >> 3);
    const int nbn = N >> 8;
    const int bm = bid / nbn, bn = bid % nbn;
    const int row0 = bm << 8, col0 = bn << 8;

    const int lr = lane & 15;
    const int lk16 = (lane >> 4) * 16;   // byte offset of this lane-group's K-chunk

    // per-lane base pointers (A-frag row block for this wave; B row block)
    const u8* apb = A + (size_t)(row0 + wm * 64 + lr) * K + lk16;
    const u8* bpb = Bq + (size_t)(col0 + wn * 64 + lr) * K + lk16;

    i32x4 acc[8][4] = {};
    i32x4 av[8][2], bv[4][2];
    const int NT = K >> 7;               // 16 tiles of K=128 (K % 256 == 0 guaranteed)

    // ---- prologue: load tile 0 fully into registers
    GLOAD_A_KS(0, 0); GLOAD_B_KS(0, 0);
    GLOAD_A_KS(1, 0); GLOAD_B_KS(1, 0);

    for (int t = 0; t < NT; ++t) {
        const size_t kbn = (size_t)(t + 1 < NT ? t + 1 : NT - 1) << 7;  // clamped tail

        MFMA_HALF(0);                    // consumes av/bv[.][0]
        SB;
        GLOAD_A_KS(0, kbn);              // reload ks0 frags for t+1 (WAR after MFMA_HALF(0))
        GLOAD_B_KS(0, kbn);
        SB;
        MFMA_HALF(1);                    // consumes av/bv[.][1]
        SB;
        GLOAD_A_KS(1, kbn);
        GLOAD_B_KS(1, kbn);
        SB;
    }
    asm volatile("s_waitcnt vmcnt(0)" ::: "memory");   // drain dead tail prefetches

    // ---- epilogue: C/D layout col = lane&15, row = (lane>>4)*4 + reg (shape-determined,
    //      dtype-independent incl. i8). i32 -> f32 exact (|acc| <= 2048).
#pragma unroll
    for (int m = 0; m < 8; ++m) {
        const int grow = row0 + (m >> 2) * 128 + wm * 64 + (m & 3) * 16 + (lane >> 4) * 4;
#pragma unroll
        for (int n = 0; n < 4; ++n) {
            float* cp = C + (size_t)grow * N + col0 + wn * 64 + n * 16 + (lane & 15);
#pragma unroll
            for (int r = 0; r < 4; ++r)
                cp[(size_t)r * N] = (float)acc[m][n][r];
        }
    }
}

// ---------------- correct-but-slow fallback if workspace is tiny ----------------

__global__ void knaive(const float* __restrict__ X, const float* __restrict__ W,
                       const float* __restrict__ gptr, float* __restrict__ out,
                       int N, int K) {
    size_t idx = (size_t)blockIdx.x * blockDim.x + threadIdx.x;
    const int m = (int)(idx / N), n = (int)(idx % N);
    const float g = *gptr;
    const float* xr = X + (size_t)m * K;
    const float* wrow = W + (size_t)n * K;
    float acc = 0.f;
    for (int k = 0; k < K; ++k) {
        float xv = xr[k];
        float xs = (xv > 0.f) ? 1.f : ((xv < 0.f) ? -1.f : 0.f);
        float w = wrow[k];
        float wq = (rintf(fabsf(w) / g) >= 1.f) ? ((w < 0.f) ? -1.f : 1.f) : 0.f;
        acc += xs * wq;
    }
    out[idx] = acc;
}

// ---------------- launch ----------------

extern "C" void kernel_launch(void* const* d_in, const int* in_sizes, int n_in,
                              void* d_out, int out_size, void* d_ws, size_t ws_size,
                              hipStream_t stream) {
    const float* x = (const float*)d_in[0];
    const float* W = (const float*)d_in[1];
    float* out = (float*)d_out;

    const int K = 2048;                 // in_features
    const int N = in_sizes[1] / K;      // out_features = 2048
    const int M = in_sizes[0] / K;      // 4*4096 = 16384
    const int nW = in_sizes[1];

    char* ws = (char*)d_ws;
    double* partials = (double*)ws;                       // 1024 doubles = 8 KB
    float* gamma = (float*)(ws + 8192);
    u8* wq = (u8*)(ws + 16384);
    u8* xq = (u8*)(ws + 16384 + (size_t)N * K);
    const size_t need = 16384 + (size_t)N * K + (size_t)M * K;

    kabs_partial<<<1024, 256, 0, stream>>>(W, partials, nW);
    kgamma<<<1, 256, 0, stream>>>(partials, gamma, nW);

    if (ws_size >= need && (M % 256) == 0 && (N % 256) == 0 && (K % 256) == 0) {
        kquant_w<<<nW / (256 * 4), 256, 0, stream>>>((const float4*)W, (unsigned int*)wq,
                                                     gamma, nW / 4);
        const size_t n16 = (size_t)M * K / 16;
        kquant_x<<<(unsigned)((n16 + 255) / 256), 256, 0, stream>>>(
            (const float4*)x, (uint4*)xq, n16);
        kgemm<<<(M / 256) * (N / 256), 512, 0, stream>>>(xq, wq, out, M, N, K);
    } else {
        knaive<<<(unsigned)((size_t)M * N / 256), 256, 0, stream>>>(x, W, gamma, out, N, K);
    }
}

// Round 18
// 200.576 us; speedup vs baseline: 1.2280x; 1.2280x over previous
//
#include <hip/hip_runtime.h>
#include <hip/hip_bf16.h>

typedef __attribute__((ext_vector_type(4))) int i32x4;
typedef unsigned char u8;

// ---------------- gamma = mean(|W|) + 1e-6, deterministic two-stage ----------------

__global__ void kabs_partial(const float* __restrict__ W, double* __restrict__ part, int n) {
    __shared__ double sd[256];
    const int tid = threadIdx.x;
    double s = 0.0;
    for (int i = blockIdx.x * blockDim.x + tid; i < n; i += gridDim.x * blockDim.x)
        s += (double)fabsf(W[i]);
    sd[tid] = s;
    __syncthreads();
    for (int off = 128; off > 0; off >>= 1) {
        if (tid < off) sd[tid] += sd[tid + off];
        __syncthreads();
    }
    if (tid == 0) part[blockIdx.x] = sd[0];
}

__global__ void kgamma(const double* __restrict__ part, float* __restrict__ gout, int nelem) {
    __shared__ double sd[256];
    const int tid = threadIdx.x;
    double s = part[tid] + part[tid + 256] + part[tid + 512] + part[tid + 768];
    sd[tid] = s;
    __syncthreads();
    for (int off = 128; off > 0; off >>= 1) {
        if (tid < off) sd[tid] += sd[tid + off];
        __syncthreads();
    }
    if (tid == 0) gout[0] = (float)(sd[0] / (double)nelem) + 1e-6f;
}

// ---------------- quantizers: write i8 {-1,0,+1} ----------------

__device__ __forceinline__ unsigned int qw_b(float w, float g) {
    float t = fabsf(w) / g;
    unsigned int u = __float_as_uint(w);
    return (rintf(t) >= 1.0f) ? ((u >> 31) ? 0xFFu : 0x01u) : 0u;
}

__global__ void kquant_w(const float4* __restrict__ W4, unsigned int* __restrict__ Wq,
                         const float* __restrict__ gptr, int n4) {
    int i = blockIdx.x * blockDim.x + threadIdx.x;
    if (i >= n4) return;
    const float g = *gptr;
    float4 w = W4[i];
    Wq[i] = qw_b(w.x, g) | (qw_b(w.y, g) << 8) | (qw_b(w.z, g) << 16) | (qw_b(w.w, g) << 24);
}

__device__ __forceinline__ unsigned int sgn_b(float a) {
    unsigned int u = __float_as_uint(a);
    return (u & 0x7FFFFFFFu) ? ((u >> 31) ? 0xFFu : 0x01u) : 0u;
}
__device__ __forceinline__ unsigned int sgn4(float4 v) {
    return sgn_b(v.x) | (sgn_b(v.y) << 8) | (sgn_b(v.z) << 16) | (sgn_b(v.w) << 24);
}

__global__ void kquant_x(const float4* __restrict__ X4, uint4* __restrict__ Xq, size_t n16) {
    size_t i = (size_t)blockIdx.x * blockDim.x + threadIdx.x;
    if (i >= n16) return;
    uint4 o;
    o.x = sgn4(X4[4 * i]);
    o.y = sgn4(X4[4 * i + 1]);
    o.z = sgn4(X4[4 * i + 2]);
    o.w = sgn4(X4[4 * i + 3]);
    Xq[i] = o;
}

// ---------------- 128x128 i8 MFMA GEMM: A-only LDS (32KB), B from L2, 4 waves ----------
// C[M][N] = A[M][K] * B[N][K]^T, A/B i8 {-1,0,+1}, acc i32 (exact), out f32.
// R17 bug: GLOAD_B_KS issues 4 loads (not 8) -> outstanding at certify = 16, so
// vmcnt(20) NEVER waited -> A(t) stage uncertified -> absmax 2723. Fix: vmcnt(12).
// Ledger (steady state, oldest->newest at certify of tile t):
//   [stageA(t)=4 | bv0(t)=4 | bv1(t)=4 | stageA(t+1)=4] = 16
// vmcnt(12) drains exactly stageA(t), issued one full tile (~2000cyc) earlier.
// bv(t) waits are compiler-tracked (VGPR loads, proven R15). Never 0 in loop.
// Design rationale (R12-R16): wave 64x64 acc=64 regs + av 32 + bv 32 => ~155 VGPR ->
// 3 blocks/CU drift freely (m114 overlap); A in LDS w/ R12 swizzle (0 conflicts);
// B fragments = 16 rows x 64 contiguous bytes from L2-resident wq (4MB).
// Race audit (R11 invariant): A(t) reads in [B1(t),B2(t)); restage of that buffer at
// top of t+1, after B2(t) -> >=1 barrier. bv reload issues after its last consuming
// MFMA (SB-fenced). Tail: clamped kb re-stages/re-loads tile NT-1 (dead, count-exact).

#define SB __builtin_amdgcn_sched_barrier(0)
#define BARRIER do { asm volatile("" ::: "memory"); __builtin_amdgcn_s_barrier(); \
                     asm volatile("" ::: "memory"); } while (0)
#define LGKM0   do { asm volatile("s_waitcnt lgkmcnt(0)" ::: "memory"); \
                     __builtin_amdgcn_sched_barrier(0); } while (0)

#define STAGE_A(BUF, KB)                                                                    \
    {                                                                                       \
        _Pragma("unroll")                                                                   \
        for (int l = 0; l < 4; ++l) {                                                       \
            const int r_ = l * 32 + srow;                                                   \
            const u8* g_ = A + (size_t)(row0 + r_) * K + (KB) + (sec ^ ((r_ & 7) << 4));    \
            __builtin_amdgcn_global_load_lds(                                               \
                (const __attribute__((address_space(1))) unsigned int*)g_,                  \
                (__attribute__((address_space(3))) unsigned int*)&As[BUF][r_][sec],         \
                16, 0, 0);                                                                  \
        }                                                                                   \
    }

#define DS_READ_A8(BUF)                                                                     \
    {                                                                                       \
        _Pragma("unroll")                                                                   \
        for (int mi = 0; mi < 4; ++mi) {                                                    \
            const int ra = wm * 64 + mi * 16 + lr;                                          \
            _Pragma("unroll")                                                               \
            for (int ks = 0; ks < 2; ++ks)                                                  \
                av[mi][ks] = *(const i32x4*)&As[BUF][ra]                                    \
                                 [(ks * 64 + lk16) ^ ((ra & 7) << 4)];                      \
        }                                                                                   \
    }

#define GLOAD_B_KS(KS, KB)                                                                  \
    {                                                                                       \
        _Pragma("unroll")                                                                   \
        for (int n = 0; n < 4; ++n)                                                         \
            bv[n][KS] = *(const i32x4*)&Bq[(size_t)(brow + n * 16) * K + (KB) +             \
                                           (KS) * 64 + lk16];                               \
    }

#define MFMA16(KS)                                                                          \
    do {                                                                                    \
        __builtin_amdgcn_s_setprio(1);                                                      \
        _Pragma("unroll")                                                                   \
        for (int mi = 0; mi < 4; ++mi)                                                      \
            _Pragma("unroll")                                                               \
            for (int n = 0; n < 4; ++n)                                                     \
                acc[mi][n] = __builtin_amdgcn_mfma_i32_16x16x64_i8(                         \
                    av[mi][KS], bv[n][KS], acc[mi][n], 0, 0, 0);                            \
        __builtin_amdgcn_s_setprio(0);                                                      \
    } while (0)

__global__ __launch_bounds__(256, 2) void kgemm(const u8* __restrict__ A,
                                                const u8* __restrict__ Bq,
                                                float* __restrict__ C,
                                                int M, int N, int K) {
    __shared__ u8 As[2][128][128];       // A only: 32 KB

    const int tid = threadIdx.x;
    const int lane = tid & 63;
    const int wid = tid >> 6;      // 0..3
    const int wm = wid >> 1;       // 0..1  (M sub-block)
    const int wn = wid & 1;        // 0..1  (N sub-block)

    // T1: XCD-aware block swizzle (grid % 8 == 0 here)
    int bid = blockIdx.x;
    const int nwg = gridDim.x;
    if ((nwg & 7) == 0) bid = (bid & 7) * (nwg >> 3) + (bid >> 3);
    const int nbn = N >> 7;
    const int bm = bid / nbn, bn = bid % nbn;
    const int row0 = bm << 7, col0 = bn << 7;

    const int lr = lane & 15;
    const int lk16 = (lane >> 4) * 16;   // byte offset of this lane-group's K-chunk
    const int brow = col0 + wn * 64 + lr;

    // staging thread mapping: 256 threads cover 32 rows x 128 bytes per load instr
    const int srow = tid >> 3;           // 0..31
    const int sec  = (tid & 7) * 16;     // 16-byte chunk within the 128B row

    i32x4 acc[4][4] = {};
    i32x4 av[4][2], bv[4][2];
    const int NT = K >> 7;               // 16 tiles of K=128 (K % 256 == 0 guaranteed)

    // ---- prologue: stage tile0's A; load tile0's B
    STAGE_A(0, 0);
    GLOAD_B_KS(0, 0);
    GLOAD_B_KS(1, 0);

    for (int t = 0; t < NT; ++t) {
        const int cb = t & 1, nb = cb ^ 1;
        const int kbn = (t + 1 < NT ? t + 1 : NT - 1) << 7;   // clamped tail (dead)

        STAGE_A(nb, kbn);                                     // 4 gload_lds
        asm volatile("s_waitcnt vmcnt(12)" ::: "memory");     // certify A(t) stage (R17 fix)
        BARRIER;                                              // B1

        DS_READ_A8(cb);
        LGKM0;
        MFMA16(0);                       // consumes av[.][0], bv[.][0] (compiler waits bv)
        SB;
        GLOAD_B_KS(0, kbn);              // reload bv ks0 for t+1 (after last use)
        SB;
        MFMA16(1);                       // consumes av[.][1], bv[.][1]
        SB;
        GLOAD_B_KS(1, kbn);
        SB;
        BARRIER;                         // B2: separates A(t) reads from next restage
    }
    asm volatile("s_waitcnt vmcnt(0) lgkmcnt(0)" ::: "memory");

    // ---- epilogue: C/D layout col = lane&15, row = (lane>>4)*4 + reg (shape-determined,
    //      dtype-independent incl. i8). i32 -> f32 exact (|acc| <= 2048).
#pragma unroll
    for (int m = 0; m < 4; ++m) {
        const int grow = row0 + wm * 64 + m * 16 + (lane >> 4) * 4;
#pragma unroll
        for (int n = 0; n < 4; ++n) {
            float* cp = C + (size_t)grow * N + col0 + wn * 64 + n * 16 + (lane & 15);
#pragma unroll
            for (int r = 0; r < 4; ++r)
                cp[(size_t)r * N] = (float)acc[m][n][r];
        }
    }
}

// ---------------- correct-but-slow fallback if workspace is tiny ----------------

__global__ void knaive(const float* __restrict__ X, const float* __restrict__ W,
                       const float* __restrict__ gptr, float* __restrict__ out,
                       int N, int K) {
    size_t idx = (size_t)blockIdx.x * blockDim.x + threadIdx.x;
    const int m = (int)(idx / N), n = (int)(idx % N);
    const float g = *gptr;
    const float* xr = X + (size_t)m * K;
    const float* wrow = W + (size_t)n * K;
    float acc = 0.f;
    for (int k = 0; k < K; ++k) {
        float xv = xr[k];
        float xs = (xv > 0.f) ? 1.f : ((xv < 0.f) ? -1.f : 0.f);
        float w = wrow[k];
        float wq = (rintf(fabsf(w) / g) >= 1.f) ? ((w < 0.f) ? -1.f : 1.f) : 0.f;
        acc += xs * wq;
    }
    out[idx] = acc;
}

// ---------------- launch ----------------

extern "C" void kernel_launch(void* const* d_in, const int* in_sizes, int n_in,
                              void* d_out, int out_size, void* d_ws, size_t ws_size,
                              hipStream_t stream) {
    const float* x = (const float*)d_in[0];
    const float* W = (const float*)d_in[1];
    float* out = (float*)d_out;

    const int K = 2048;                 // in_features
    const int N = in_sizes[1] / K;      // out_features = 2048
    const int M = in_sizes[0] / K;      // 4*4096 = 16384
    const int nW = in_sizes[1];

    char* ws = (char*)d_ws;
    double* partials = (double*)ws;                       // 1024 doubles = 8 KB
    float* gamma = (float*)(ws + 8192);
    u8* wq = (u8*)(ws + 16384);
    u8* xq = (u8*)(ws + 16384 + (size_t)N * K);
    const size_t need = 16384 + (size_t)N * K + (size_t)M * K;

    kabs_partial<<<1024, 256, 0, stream>>>(W, partials, nW);
    kgamma<<<1, 256, 0, stream>>>(partials, gamma, nW);

    if (ws_size >= need && (M % 128) == 0 && (N % 128) == 0 && (K % 256) == 0) {
        kquant_w<<<nW / (256 * 4), 256, 0, stream>>>((const float4*)W, (unsigned int*)wq,
                                                     gamma, nW / 4);
        const size_t n16 = (size_t)M * K / 16;
        kquant_x<<<(unsigned)((n16 + 255) / 256), 256, 0, stream>>>(
            (const float4*)x, (uint4*)xq, n16);
        kgemm<<<(M / 128) * (N / 128), 256, 0, stream>>>(xq, wq, out, M, N, K);
    } else {
        knaive<<<(unsigned)((size_t)M * N / 256), 256, 0, stream>>>(x, W, gamma, out, N, K);
    }
}